// Round 9
// baseline (90.672 us; speedup 1.0000x reference)
//
#include <hip/hip_runtime.h>

#define EPS 1e-4f

constexpr int B  = 8;
constexpr int C  = 128;
constexpr int Tt = 9;
constexpr int T  = 8;
constexpr int H  = 64;
constexpr int W  = 64;
constexpr int HW = H * W;          // 4096
constexpr int HM = 256;
constexpr int WM = 256;
constexpr int HWM = HM * WM;       // 65536

typedef __attribute__((ext_vector_type(4))) float f32x4;

// ws float region. Every cell written before read each replay.
constexpr int WS_GSP   = 0;                    // gs partials [b][c2(64)][t] = 4096
constexpr int WS_VSP   = WS_GSP + B * 64 * T;  // vs partials [bt][q8] = 512
constexpr int WS_END_F = WS_VSP + B * T * 8;
// byte regions (offsets from ws + WS_END_F floats)
constexpr int WSB_RV  = 0;                     // rv bytes  B*T*HW = 256 KB
constexpr int WSB_VM  = WSB_RV + B * T * HW;   // vm bytes  B*T*HW = 256 KB
constexpr int WSB_STG = WSB_VM + B * T * HW;   // staged rf bf16 [b][c][t][hw] = 64 MB

__device__ __forceinline__ const f32x4& ld4(const float* p) {
  return *reinterpret_cast<const f32x4*>(p);
}
__device__ __forceinline__ void st4(float* p, f32x4 v) {
  *reinterpret_cast<f32x4*>(p) = v;
}
__device__ __forceinline__ unsigned short f2bf(float x) {  // RNE f32->bf16
  unsigned int u = __float_as_uint(x);
  return (unsigned short)((u + 0x7FFFu + ((u >> 16) & 1u)) >> 16);
}
__device__ __forceinline__ float bf2f(unsigned short s) {
  return __uint_as_float(((unsigned int)s) << 16);
}

// --- antialiased bilinear downsample 256 -> 64 (scale 1/4), one output pixel.
// jax.image.resize 'bilinear' antialias=True: sample = 4o+1.5, taps 4o-2..4o+5,
// unnormalized weights {1,3,5,7,7,5,3,1}, per-dim renormalized over valid taps.
__device__ __forceinline__ float resample_px(const float* __restrict__ src,
                                             int y, int x) {
  const float wt[8] = {1.f, 3.f, 5.f, 7.f, 7.f, 5.f, 3.f, 1.f};
  int by = 4 * y - 2, bx = 4 * x - 2;
  float wx[8];
  float nx = 0.f;
  #pragma unroll
  for (int d = 0; d < 8; ++d) {
    int xx = bx + d;
    float w = (xx >= 0 && xx < WM) ? wt[d] : 0.f;
    wx[d] = w;
    nx += w;
  }
  float ny = 0.f;
  float sum = 0.f;
  #pragma unroll
  for (int dy = 0; dy < 8; ++dy) {
    int yy = by + dy;
    if (yy < 0 || yy >= HM) continue;
    ny += wt[dy];
    const float* row = src + yy * WM;
    float rowsum = 0.f;
    #pragma unroll
    for (int dx = 0; dx < 8; ++dx) {
      int xx = bx + dx;
      xx = xx < 0 ? 0 : (xx >= WM ? WM - 1 : xx);  // clamp addr; weight 0 if OOB
      rowsum += wx[dx] * row[xx];
    }
    sum += wt[dy] * rowsum;
  }
  return sum / (ny * nx);
}

// Kernel A: rv bytes + vm bytes + vs counts. grid = bt(64) x q(8) = 512 blocks.
__global__ __launch_bounds__(256) void mask_kernel(
    const float* __restrict__ tvmap, const float* __restrict__ rvmaps,
    float* __restrict__ ws) {
  int bid = blockIdx.x;
  int q = bid & 7, bt = bid >> 3;
  int b = bt >> 3;
  int tid = threadIdx.x;

  unsigned char* wsb = (unsigned char*)(ws + WS_END_F);
  const float* tsrc = tvmap + (size_t)b * HWM;
  const float* rsrc = rvmaps + (size_t)bt * HWM;
  unsigned char* rvb = wsb + WSB_RV + bt * HW;
  unsigned char* vmb = wsb + WSB_VM + bt * HW;

  int cnt = 0;
  #pragma unroll
  for (int k = 0; k < 2; ++k) {
    int px = q * 512 + k * 256 + tid;
    int y = px >> 6, x = px & 63;
    float tv = resample_px(tsrc, y, x);
    float rv = resample_px(rsrc, y, x);
    unsigned char rb = rv > 0.5f ? 1 : 0;
    unsigned char v = (tv > 0.5f) ? rb : 0;
    rvb[px] = rb;
    vmb[px] = v;
    cnt += v;
  }

  float fc = (float)cnt;
  #pragma unroll
  for (int m = 32; m > 0; m >>= 1) fc += __shfl_xor(fc, m);
  __shared__ float red[4];
  int lane = tid & 63, wave = tid >> 6;
  if (lane == 0) red[wave] = fc;
  __syncthreads();
  if (tid == 0)
    ws[WS_VSP + bt * 8 + q] = red[0] + red[1] + red[2] + red[3];
}

// Kernel B: gs partials + t_feat copy to out + rf staged to bf16.
// grid = b(8) x c2(64) = 512 blocks x 512 threads (R3's proven structure).
__global__ __launch_bounds__(512) void gs_kernel(
    const float* __restrict__ values, float* __restrict__ ws,
    float* __restrict__ out) {
  int bid = blockIdx.x;
  int c2 = bid & 63, b = bid >> 6;
  int tid = threadIdx.x;

  const unsigned char* vmb =
      (const unsigned char*)(ws + WS_END_F) + WSB_VM + b * T * HW;
  unsigned short* stg =
      (unsigned short*)((unsigned char*)(ws + WS_END_F) + WSB_STG);

  float acc[T];
  #pragma unroll
  for (int t = 0; t < T; ++t) acc[t] = 0.f;

  const float* vb = values + (size_t)(b * C + c2 * 2) * Tt * HW;

  #pragma unroll
  for (int pq = 0; pq < 2; ++pq) {
    int px = pq * 2048 + tid * 4;
    uchar4 u[T];
    #pragma unroll
    for (int t = 0; t < T; ++t)
      u[t] = *reinterpret_cast<const uchar4*>(vmb + t * HW + px);

    #pragma unroll
    for (int ci = 0; ci < 2; ++ci) {
      int c = c2 * 2 + ci;
      const float* vc = vb + (size_t)ci * Tt * HW;
      f32x4 tf = ld4(vc + px);
      st4(out + ((size_t)b * 257 + c) * HW + px, tf);   // exact t_feat copy
      #pragma unroll
      for (int t = 0; t < T; ++t) {
        f32x4 rf = ld4(vc + (t + 1) * HW + px);
        acc[t] += (u[t].x ? tf[0] * rf[0] : 0.f) +
                  (u[t].y ? tf[1] * rf[1] : 0.f) +
                  (u[t].z ? tf[2] * rf[2] : 0.f) +
                  (u[t].w ? tf[3] * rf[3] : 0.f);
        ushort4 sv;
        sv.x = f2bf(rf[0]); sv.y = f2bf(rf[1]);
        sv.z = f2bf(rf[2]); sv.w = f2bf(rf[3]);
        *reinterpret_cast<ushort4*>(
            stg + ((size_t)(b * C + c) * T + t) * HW + px) = sv;
      }
    }
  }

  __shared__ float red[8][T];
  int lane = tid & 63, wave = tid >> 6;
  #pragma unroll
  for (int t = 0; t < T; ++t) {
    float v = acc[t];
    #pragma unroll
    for (int m = 32; m > 0; m >>= 1) v += __shfl_xor(v, m);
    if (lane == 0) red[wave][t] = v;
  }
  __syncthreads();
  if (tid < T) {
    float s = 0.f;
    #pragma unroll
    for (int w = 0; w < 8; ++w) s += red[w][tid];
    ws[WS_GSP + (b * 64 + c2) * T + tid] = s;
  }
}

// Kernel C: finalize gs (redundant, tiny) + lean softmax + c_out (from staged
// bf16) + c_mask. grid = b(8) x cc(32) x hq(4) = 1024 blocks x 256 thr.
__global__ __launch_bounds__(256) void out_kernel(
    const float* __restrict__ ws_c, float* __restrict__ out) {
  const float* ws = ws_c;
  int bid = blockIdx.x;
  int hq = bid & 3, cc = (bid >> 2) & 31, b = bid >> 7;
  int tid = threadIdx.x;
  int px = hq * 1024 + tid * 4;

  __shared__ float gsf_sh[T];
  if (tid < 64) {
    int t = tid >> 3, part = tid & 7;
    float s = 0.f;
    #pragma unroll
    for (int k = 0; k < 8; ++k)
      s += ws[WS_GSP + (b * 64 + part * 8 + k) * T + t];
    #pragma unroll
    for (int m = 1; m < 8; m <<= 1) s += __shfl_xor(s, m);
    if (part == 0) {
      float vs = 0.f;
      #pragma unroll
      for (int qq = 0; qq < 8; ++qq) vs += ws[WS_VSP + (b * T + t) * 8 + qq];
      bool zero = vs < EPS;           // vs is an exact integer-valued count
      float g = zero ? 0.f : s;
      vs += zero ? 1.f : 0.f;
      gsf_sh[t] = g / vs / (float)C;
    }
  }
  __syncthreads();

  float gsf[T];
  #pragma unroll
  for (int t = 0; t < T; ++t) gsf[t] = gsf_sh[t];

  const unsigned char* rvb =
      (const unsigned char*)(ws + WS_END_F) + WSB_RV + b * T * HW;
  uchar4 ub[T];
  #pragma unroll
  for (int t = 0; t < T; ++t)
    ub[t] = *reinterpret_cast<const uchar4*>(rvb + t * HW + px);

  // masked_vec[t] = rv ? gsf[t] : 0 ; max over ALL t (zeros participate)
  f32x4 mx;
  mx[0] = ub[0].x ? gsf[0] : 0.f;
  mx[1] = ub[0].y ? gsf[0] : 0.f;
  mx[2] = ub[0].z ? gsf[0] : 0.f;
  mx[3] = ub[0].w ? gsf[0] : 0.f;
  #pragma unroll
  for (int t = 1; t < T; ++t) {
    mx[0] = fmaxf(mx[0], ub[t].x ? gsf[t] : 0.f);
    mx[1] = fmaxf(mx[1], ub[t].y ? gsf[t] : 0.f);
    mx[2] = fmaxf(mx[2], ub[t].z ? gsf[t] : 0.f);
    mx[3] = fmaxf(mx[3], ub[t].w ? gsf[t] : 0.f);
  }

  f32x4 cm[T];
  f32x4 s = {0.f, 0.f, 0.f, 0.f};
  #pragma unroll
  for (int t = 0; t < T; ++t) {
    cm[t][0] = ub[t].x ? __expf(gsf[t] - mx[0]) : 0.f;
    cm[t][1] = ub[t].y ? __expf(gsf[t] - mx[1]) : 0.f;
    cm[t][2] = ub[t].z ? __expf(gsf[t] - mx[2]) : 0.f;
    cm[t][3] = ub[t].w ? __expf(gsf[t] - mx[3]) : 0.f;
    s += cm[t];
  }
  #pragma unroll
  for (int j = 0; j < 4; ++j) {
    s[j] += (s[j] < EPS) ? 1.f : 0.f;
    s[j] = 1.f / s[j];
  }
  f32x4 csum = {0.f, 0.f, 0.f, 0.f};
  #pragma unroll
  for (int t = 0; t < T; ++t) {
    cm[t] *= s;
    csum += cm[t];
  }

  if (cc == 0) {
    f32x4 cmask;
    #pragma unroll
    for (int j = 0; j < 4; ++j) cmask[j] = 1.f - csum[j];
    st4(out + ((size_t)b * 257 + 256) * HW + px, cmask);
    st4(out + (size_t)B * 257 * HW + (size_t)b * HW + px, cmask);
  }

  const unsigned short* stg =
      (const unsigned short*)((const unsigned char*)(ws + WS_END_F) + WSB_STG);
  #pragma unroll
  for (int c = 0; c < 4; ++c) {
    int ch = cc * 4 + c;
    const unsigned short* sc = stg + (size_t)(b * C + ch) * T * HW;
    f32x4 acc = {0.f, 0.f, 0.f, 0.f};
    #pragma unroll
    for (int t = 0; t < T; ++t) {
      ushort4 sv = *reinterpret_cast<const ushort4*>(sc + t * HW + px);
      acc[0] += bf2f(sv.x) * cm[t][0];
      acc[1] += bf2f(sv.y) * cm[t][1];
      acc[2] += bf2f(sv.z) * cm[t][2];
      acc[3] += bf2f(sv.w) * cm[t][3];
    }
    st4(out + ((size_t)b * 257 + 128 + ch) * HW + px, acc);
  }
}

extern "C" void kernel_launch(void* const* d_in, const int* in_sizes, int n_in,
                              void* d_out, int out_size, void* d_ws, size_t ws_size,
                              hipStream_t stream) {
  const float* values = (const float*)d_in[0];
  const float* tvmap  = (const float*)d_in[1];
  const float* rvmaps = (const float*)d_in[2];
  float* out = (float*)d_out;
  float* ws  = (float*)d_ws;

  hipLaunchKernelGGL(mask_kernel, dim3(512), dim3(256), 0, stream,
                     tvmap, rvmaps, ws);
  hipLaunchKernelGGL(gs_kernel, dim3(512), dim3(512), 0, stream,
                     values, ws, out);
  hipLaunchKernelGGL(out_kernel, dim3(1024), dim3(256), 0, stream,
                     ws, out);
}

// Round 10
// 83.007 us; speedup vs baseline: 1.0923x; 1.0923x over previous
//
#include <hip/hip_runtime.h>

#define EPS 1e-4f

constexpr int B  = 8;
constexpr int C  = 128;
constexpr int Tt = 9;
constexpr int T  = 8;
constexpr int H  = 64;
constexpr int W  = 64;
constexpr int HW = H * W;          // 4096
constexpr int HM = 256;
constexpr int WM = 256;
constexpr int HWM = HM * WM;       // 65536

typedef __attribute__((ext_vector_type(4))) float f32x4;

// ws float region. Every cell written before read each replay — no state.
constexpr int WS_GSP   = 0;                    // gs partials [b][cc16*4+hq][t] = 4096
constexpr int WS_VSP   = WS_GSP + B * 64 * T;  // vs partials [bt][q8] = 512
constexpr int WS_END_F = WS_VSP + B * T * 8;
// byte regions (offsets from ws + WS_END_F floats)
constexpr int WSB_RV = 0;                      // rv bytes  B*T*HW = 256 KB
constexpr int WSB_VM = WSB_RV + B * T * HW;    // vm bytes  B*T*HW = 256 KB

__device__ __forceinline__ const f32x4& ld4(const float* p) {
  return *reinterpret_cast<const f32x4*>(p);
}
__device__ __forceinline__ void st4(float* p, f32x4 v) {
  *reinterpret_cast<f32x4*>(p) = v;
}
__device__ __forceinline__ f32x4 ld4nt(const float* p) {
  return __builtin_nontemporal_load(reinterpret_cast<const f32x4*>(p));
}
__device__ __forceinline__ void st4nt(float* p, f32x4 v) {
  __builtin_nontemporal_store(v, reinterpret_cast<f32x4*>(p));
}

// --- antialiased bilinear downsample 256 -> 64 (scale 1/4), one output pixel.
// jax.image.resize 'bilinear' antialias=True: sample = 4o+1.5, taps 4o-2..4o+5,
// unnormalized weights {1,3,5,7,7,5,3,1}, per-dim renormalized over valid taps.
__device__ __forceinline__ float resample_px(const float* __restrict__ src,
                                             int y, int x) {
  const float wt[8] = {1.f, 3.f, 5.f, 7.f, 7.f, 5.f, 3.f, 1.f};
  int by = 4 * y - 2, bx = 4 * x - 2;
  float wx[8];
  float nx = 0.f;
  #pragma unroll
  for (int d = 0; d < 8; ++d) {
    int xx = bx + d;
    float w = (xx >= 0 && xx < WM) ? wt[d] : 0.f;
    wx[d] = w;
    nx += w;
  }
  float ny = 0.f;
  float sum = 0.f;
  #pragma unroll
  for (int dy = 0; dy < 8; ++dy) {
    int yy = by + dy;
    if (yy < 0 || yy >= HM) continue;
    ny += wt[dy];
    const float* row = src + yy * WM;
    float rowsum = 0.f;
    #pragma unroll
    for (int dx = 0; dx < 8; ++dx) {
      int xx = bx + dx;
      xx = xx < 0 ? 0 : (xx >= WM ? WM - 1 : xx);  // clamp addr; weight 0 if OOB
      rowsum += wx[dx] * row[xx];
    }
    sum += wt[dy] * rowsum;
  }
  return sum / (ny * nx);
}

// Kernel A: rv bytes + vm bytes + vs counts. grid = bt(64) x q(8) = 512 blocks.
__global__ __launch_bounds__(256) void mask_kernel(
    const float* __restrict__ tvmap, const float* __restrict__ rvmaps,
    float* __restrict__ ws) {
  int bid = blockIdx.x;
  int q = bid & 7, bt = bid >> 3;
  int b = bt >> 3;
  int tid = threadIdx.x;

  unsigned char* wsb = (unsigned char*)(ws + WS_END_F);
  const float* tsrc = tvmap + (size_t)b * HWM;
  const float* rsrc = rvmaps + (size_t)bt * HWM;
  unsigned char* rvb = wsb + WSB_RV + bt * HW;
  unsigned char* vmb = wsb + WSB_VM + bt * HW;

  int cnt = 0;
  #pragma unroll
  for (int k = 0; k < 2; ++k) {
    int px = q * 512 + k * 256 + tid;
    int y = px >> 6, x = px & 63;
    float tv = resample_px(tsrc, y, x);
    float rv = resample_px(rsrc, y, x);
    unsigned char rb = rv > 0.5f ? 1 : 0;
    unsigned char v = (tv > 0.5f) ? rb : 0;
    rvb[px] = rb;
    vmb[px] = v;
    cnt += v;
  }

  float fc = (float)cnt;
  #pragma unroll
  for (int m = 32; m > 0; m >>= 1) fc += __shfl_xor(fc, m);
  __shared__ float red[4];
  int lane = tid & 63, wave = tid >> 6;
  if (lane == 0) red[wave] = fc;
  __syncthreads();
  if (tid == 0)
    ws[WS_VSP + bt * 8 + q] = red[0] + red[1] + red[2] + red[3];
}

// Kernel B: gs partials. R3's proven geometry: grid = b(8) x cc(16) x hq(4)
// = 512 blocks x 256 threads, 8 channels per block, hq-quartered planes.
// Byte vm masks (L2-hot, low VGPR).
__global__ __launch_bounds__(256) void gs_kernel(
    const float* __restrict__ values, float* __restrict__ ws) {
  int bid = blockIdx.x;
  int hq = bid & 3, cc = (bid >> 2) & 15, b = bid >> 6;
  int tid = threadIdx.x;
  int px = hq * 1024 + tid * 4;

  const unsigned char* vmb =
      (const unsigned char*)(ws + WS_END_F) + WSB_VM + b * T * HW;
  uchar4 u[T];
  #pragma unroll
  for (int t = 0; t < T; ++t)
    u[t] = *reinterpret_cast<const uchar4*>(vmb + t * HW + px);

  float acc[T];
  #pragma unroll
  for (int t = 0; t < T; ++t) acc[t] = 0.f;

  const float* vb = values + (size_t)(b * C + cc * 8) * Tt * HW;
  #pragma unroll
  for (int c = 0; c < 8; ++c) {
    const float* vc = vb + (size_t)c * Tt * HW;
    f32x4 tf = ld4(vc + px);
    #pragma unroll
    for (int t = 0; t < T; ++t) {
      f32x4 rf = ld4(vc + (t + 1) * HW + px);
      acc[t] += (u[t].x ? tf[0] * rf[0] : 0.f) +
                (u[t].y ? tf[1] * rf[1] : 0.f) +
                (u[t].z ? tf[2] * rf[2] : 0.f) +
                (u[t].w ? tf[3] * rf[3] : 0.f);
    }
  }

  __shared__ float red[4][T];
  int lane = tid & 63, wave = tid >> 6;
  #pragma unroll
  for (int t = 0; t < T; ++t) {
    float v = acc[t];
    #pragma unroll
    for (int m = 32; m > 0; m >>= 1) v += __shfl_xor(v, m);
    if (lane == 0) red[wave][t] = v;
  }
  __syncthreads();
  if (tid < T) {
    float s = red[0][tid] + red[1][tid] + red[2][tid] + red[3][tid];
    ws[WS_GSP + ((b * 16 + cc) * 4 + hq) * T + tid] = s;
  }
}

// Kernel C: finalize gs (redundant, tiny) + lean softmax + t_feat copy +
// c_out + c_mask. grid = b(8) x cc(32) x hq(4) = 1024 blocks x 256 thr,
// 4 channels per block. NT loads on values (dead after), NT stores on out.
__global__ __launch_bounds__(256) void out_kernel(
    const float* __restrict__ values, const float* __restrict__ ws,
    float* __restrict__ out) {
  int bid = blockIdx.x;
  int hq = bid & 3, cc = (bid >> 2) & 31, b = bid >> 7;
  int tid = threadIdx.x;
  int px = hq * 1024 + tid * 4;

  __shared__ float gsf_sh[T];
  if (tid < 64) {
    int t = tid >> 3, part = tid & 7;
    float s = 0.f;
    #pragma unroll
    for (int k = 0; k < 8; ++k)
      s += ws[WS_GSP + (part * 8 + k) * T + b * 64 * T + t];
    #pragma unroll
    for (int m = 1; m < 8; m <<= 1) s += __shfl_xor(s, m);
    if (part == 0) {
      float vs = 0.f;
      #pragma unroll
      for (int qq = 0; qq < 8; ++qq) vs += ws[WS_VSP + (b * T + t) * 8 + qq];
      bool zero = vs < EPS;           // vs is an exact integer-valued count
      float g = zero ? 0.f : s;
      vs += zero ? 1.f : 0.f;
      gsf_sh[t] = g / vs / (float)C;
    }
  }
  __syncthreads();

  float gsf[T];
  #pragma unroll
  for (int t = 0; t < T; ++t) gsf[t] = gsf_sh[t];

  const unsigned char* rvb =
      (const unsigned char*)(ws + WS_END_F) + WSB_RV + b * T * HW;
  uchar4 ub[T];
  #pragma unroll
  for (int t = 0; t < T; ++t)
    ub[t] = *reinterpret_cast<const uchar4*>(rvb + t * HW + px);

  // masked_vec[t] = rv ? gsf[t] : 0 ; max over ALL t (zeros participate)
  f32x4 mx;
  mx[0] = ub[0].x ? gsf[0] : 0.f;
  mx[1] = ub[0].y ? gsf[0] : 0.f;
  mx[2] = ub[0].z ? gsf[0] : 0.f;
  mx[3] = ub[0].w ? gsf[0] : 0.f;
  #pragma unroll
  for (int t = 1; t < T; ++t) {
    mx[0] = fmaxf(mx[0], ub[t].x ? gsf[t] : 0.f);
    mx[1] = fmaxf(mx[1], ub[t].y ? gsf[t] : 0.f);
    mx[2] = fmaxf(mx[2], ub[t].z ? gsf[t] : 0.f);
    mx[3] = fmaxf(mx[3], ub[t].w ? gsf[t] : 0.f);
  }

  f32x4 cm[T];
  f32x4 s = {0.f, 0.f, 0.f, 0.f};
  #pragma unroll
  for (int t = 0; t < T; ++t) {
    cm[t][0] = ub[t].x ? __expf(gsf[t] - mx[0]) : 0.f;
    cm[t][1] = ub[t].y ? __expf(gsf[t] - mx[1]) : 0.f;
    cm[t][2] = ub[t].z ? __expf(gsf[t] - mx[2]) : 0.f;
    cm[t][3] = ub[t].w ? __expf(gsf[t] - mx[3]) : 0.f;
    s += cm[t];
  }
  #pragma unroll
  for (int j = 0; j < 4; ++j) {
    s[j] += (s[j] < EPS) ? 1.f : 0.f;
    s[j] = 1.f / s[j];
  }
  f32x4 csum = {0.f, 0.f, 0.f, 0.f};
  #pragma unroll
  for (int t = 0; t < T; ++t) {
    cm[t] *= s;
    csum += cm[t];
  }

  if (cc == 0) {
    f32x4 cmask;
    #pragma unroll
    for (int j = 0; j < 4; ++j) cmask[j] = 1.f - csum[j];
    st4nt(out + ((size_t)b * 257 + 256) * HW + px, cmask);
    st4nt(out + (size_t)B * 257 * HW + (size_t)b * HW + px, cmask);
  }

  const float* vb = values + (size_t)(b * C + cc * 4) * Tt * HW;
  #pragma unroll
  for (int c = 0; c < 4; ++c) {
    int ch = cc * 4 + c;
    const float* vc = vb + (size_t)c * Tt * HW;
    f32x4 tf = ld4nt(vc + px);
    st4nt(out + ((size_t)b * 257 + ch) * HW + px, tf);   // exact t_feat copy
    f32x4 acc = {0.f, 0.f, 0.f, 0.f};
    #pragma unroll
    for (int t = 0; t < T; ++t) {
      f32x4 rf = ld4nt(vc + (t + 1) * HW + px);
      acc += rf * cm[t];
    }
    st4nt(out + ((size_t)b * 257 + 128 + ch) * HW + px, acc);
  }
}

extern "C" void kernel_launch(void* const* d_in, const int* in_sizes, int n_in,
                              void* d_out, int out_size, void* d_ws, size_t ws_size,
                              hipStream_t stream) {
  const float* values = (const float*)d_in[0];
  const float* tvmap  = (const float*)d_in[1];
  const float* rvmaps = (const float*)d_in[2];
  float* out = (float*)d_out;
  float* ws  = (float*)d_ws;

  hipLaunchKernelGGL(mask_kernel, dim3(512), dim3(256), 0, stream,
                     tvmap, rvmaps, ws);
  hipLaunchKernelGGL(gs_kernel, dim3(512), dim3(256), 0, stream,
                     values, ws);
  hipLaunchKernelGGL(out_kernel, dim3(1024), dim3(256), 0, stream,
                     values, ws, out);
}

// Round 11
// 79.348 us; speedup vs baseline: 1.1427x; 1.0461x over previous
//
#include <hip/hip_runtime.h>

#define EPS 1e-4f

constexpr int B  = 8;
constexpr int C  = 128;
constexpr int Tt = 9;
constexpr int T  = 8;
constexpr int H  = 64;
constexpr int W  = 64;
constexpr int HW = H * W;          // 4096
constexpr int HM = 256;
constexpr int WM = 256;
constexpr int HWM = HM * WM;       // 65536

typedef __attribute__((ext_vector_type(4))) float f32x4;

// ws float region. Every cell written before read each replay — no state.
constexpr int WS_GSP   = 0;                    // gs partials [b][cc16*4+hq][t] = 4096
constexpr int WS_VSP   = WS_GSP + B * 64 * T;  // vs partials [bt][q8] = 512
constexpr int WS_END_F = WS_VSP + B * T * 8;
// byte regions (offsets from ws + WS_END_F floats)
constexpr int WSB_RV = 0;                      // rv bytes  B*T*HW = 256 KB
constexpr int WSB_VM = WSB_RV + B * T * HW;    // vm bytes  B*T*HW = 256 KB

__device__ __forceinline__ const f32x4& ld4(const float* p) {
  return *reinterpret_cast<const f32x4*>(p);
}
__device__ __forceinline__ void st4(float* p, f32x4 v) {
  *reinterpret_cast<f32x4*>(p) = v;
}

// --- antialiased bilinear downsample 256 -> 64 (scale 1/4), one output pixel.
// jax.image.resize 'bilinear' antialias=True: sample = 4o+1.5, taps 4o-2..4o+5,
// unnormalized weights {1,3,5,7,7,5,3,1}, per-dim renormalized over valid taps.
__device__ __forceinline__ float resample_px(const float* __restrict__ src,
                                             int y, int x) {
  const float wt[8] = {1.f, 3.f, 5.f, 7.f, 7.f, 5.f, 3.f, 1.f};
  int by = 4 * y - 2, bx = 4 * x - 2;
  float wx[8];
  float nx = 0.f;
  #pragma unroll
  for (int d = 0; d < 8; ++d) {
    int xx = bx + d;
    float w = (xx >= 0 && xx < WM) ? wt[d] : 0.f;
    wx[d] = w;
    nx += w;
  }
  float ny = 0.f;
  float sum = 0.f;
  #pragma unroll
  for (int dy = 0; dy < 8; ++dy) {
    int yy = by + dy;
    if (yy < 0 || yy >= HM) continue;
    ny += wt[dy];
    const float* row = src + yy * WM;
    float rowsum = 0.f;
    #pragma unroll
    for (int dx = 0; dx < 8; ++dx) {
      int xx = bx + dx;
      xx = xx < 0 ? 0 : (xx >= WM ? WM - 1 : xx);  // clamp addr; weight 0 if OOB
      rowsum += wx[dx] * row[xx];
    }
    sum += wt[dy] * rowsum;
  }
  return sum / (ny * nx);
}

// Kernel A: rv bytes + vm bytes + vs counts. grid = bt(64) x q(8) = 512 blocks.
__global__ __launch_bounds__(256) void mask_kernel(
    const float* __restrict__ tvmap, const float* __restrict__ rvmaps,
    float* __restrict__ ws) {
  int bid = blockIdx.x;
  int q = bid & 7, bt = bid >> 3;
  int b = bt >> 3;
  int tid = threadIdx.x;

  unsigned char* wsb = (unsigned char*)(ws + WS_END_F);
  const float* tsrc = tvmap + (size_t)b * HWM;
  const float* rsrc = rvmaps + (size_t)bt * HWM;
  unsigned char* rvb = wsb + WSB_RV + bt * HW;
  unsigned char* vmb = wsb + WSB_VM + bt * HW;

  int cnt = 0;
  #pragma unroll
  for (int k = 0; k < 2; ++k) {
    int px = q * 512 + k * 256 + tid;
    int y = px >> 6, x = px & 63;
    float tv = resample_px(tsrc, y, x);
    float rv = resample_px(rsrc, y, x);
    unsigned char rb = rv > 0.5f ? 1 : 0;
    unsigned char v = (tv > 0.5f) ? rb : 0;
    rvb[px] = rb;
    vmb[px] = v;
    cnt += v;
  }

  float fc = (float)cnt;
  #pragma unroll
  for (int m = 32; m > 0; m >>= 1) fc += __shfl_xor(fc, m);
  __shared__ float red[4];
  int lane = tid & 63, wave = tid >> 6;
  if (lane == 0) red[wave] = fc;
  __syncthreads();
  if (tid == 0)
    ws[WS_VSP + bt * 8 + q] = red[0] + red[1] + red[2] + red[3];
}

// Kernel B: gs partials. R3's proven geometry: grid = b(8) x cc(16) x hq(4)
// = 512 blocks x 256 threads, 8 channels per block, hq-quartered planes.
// Byte vm masks (L2-hot, low VGPR).
__global__ __launch_bounds__(256) void gs_kernel(
    const float* __restrict__ values, float* __restrict__ ws) {
  int bid = blockIdx.x;
  int hq = bid & 3, cc = (bid >> 2) & 15, b = bid >> 6;
  int tid = threadIdx.x;
  int px = hq * 1024 + tid * 4;

  const unsigned char* vmb =
      (const unsigned char*)(ws + WS_END_F) + WSB_VM + b * T * HW;
  uchar4 u[T];
  #pragma unroll
  for (int t = 0; t < T; ++t)
    u[t] = *reinterpret_cast<const uchar4*>(vmb + t * HW + px);

  float acc[T];
  #pragma unroll
  for (int t = 0; t < T; ++t) acc[t] = 0.f;

  const float* vb = values + (size_t)(b * C + cc * 8) * Tt * HW;
  #pragma unroll
  for (int c = 0; c < 8; ++c) {
    const float* vc = vb + (size_t)c * Tt * HW;
    f32x4 tf = ld4(vc + px);
    #pragma unroll
    for (int t = 0; t < T; ++t) {
      f32x4 rf = ld4(vc + (t + 1) * HW + px);
      acc[t] += (u[t].x ? tf[0] * rf[0] : 0.f) +
                (u[t].y ? tf[1] * rf[1] : 0.f) +
                (u[t].z ? tf[2] * rf[2] : 0.f) +
                (u[t].w ? tf[3] * rf[3] : 0.f);
    }
  }

  __shared__ float red[4][T];
  int lane = tid & 63, wave = tid >> 6;
  #pragma unroll
  for (int t = 0; t < T; ++t) {
    float v = acc[t];
    #pragma unroll
    for (int m = 32; m > 0; m >>= 1) v += __shfl_xor(v, m);
    if (lane == 0) red[wave][t] = v;
  }
  __syncthreads();
  if (tid < T) {
    float s = red[0][tid] + red[1][tid] + red[2][tid] + red[3][tid];
    ws[WS_GSP + ((b * 16 + cc) * 4 + hq) * T + tid] = s;
  }
}

// Kernel C: finalize gs (redundant, tiny) + lean softmax + t_feat copy +
// c_out + c_mask. grid = b(8) x cc(32) x hq(4) = 1024 blocks x 256 thr,
// 4 channels per block. Plain cached loads — pass 2 depends on L3 residency.
__global__ __launch_bounds__(256) void out_kernel(
    const float* __restrict__ values, const float* __restrict__ ws,
    float* __restrict__ out) {
  int bid = blockIdx.x;
  int hq = bid & 3, cc = (bid >> 2) & 31, b = bid >> 7;
  int tid = threadIdx.x;
  int px = hq * 1024 + tid * 4;

  __shared__ float gsf_sh[T];
  if (tid < 64) {
    int t = tid >> 3, part = tid & 7;
    float s = 0.f;
    #pragma unroll
    for (int k = 0; k < 8; ++k)
      s += ws[WS_GSP + (b * 64 + part * 8 + k) * T + t];
    #pragma unroll
    for (int m = 1; m < 8; m <<= 1) s += __shfl_xor(s, m);
    if (part == 0) {
      float vs = 0.f;
      #pragma unroll
      for (int qq = 0; qq < 8; ++qq) vs += ws[WS_VSP + (b * T + t) * 8 + qq];
      bool zero = vs < EPS;           // vs is an exact integer-valued count
      float g = zero ? 0.f : s;
      vs += zero ? 1.f : 0.f;
      gsf_sh[t] = g / vs / (float)C;
    }
  }
  __syncthreads();

  float gsf[T];
  #pragma unroll
  for (int t = 0; t < T; ++t) gsf[t] = gsf_sh[t];

  const unsigned char* rvb =
      (const unsigned char*)(ws + WS_END_F) + WSB_RV + b * T * HW;
  uchar4 ub[T];
  #pragma unroll
  for (int t = 0; t < T; ++t)
    ub[t] = *reinterpret_cast<const uchar4*>(rvb + t * HW + px);

  // masked_vec[t] = rv ? gsf[t] : 0 ; max over ALL t (zeros participate)
  f32x4 mx;
  mx[0] = ub[0].x ? gsf[0] : 0.f;
  mx[1] = ub[0].y ? gsf[0] : 0.f;
  mx[2] = ub[0].z ? gsf[0] : 0.f;
  mx[3] = ub[0].w ? gsf[0] : 0.f;
  #pragma unroll
  for (int t = 1; t < T; ++t) {
    mx[0] = fmaxf(mx[0], ub[t].x ? gsf[t] : 0.f);
    mx[1] = fmaxf(mx[1], ub[t].y ? gsf[t] : 0.f);
    mx[2] = fmaxf(mx[2], ub[t].z ? gsf[t] : 0.f);
    mx[3] = fmaxf(mx[3], ub[t].w ? gsf[t] : 0.f);
  }

  f32x4 cm[T];
  f32x4 s = {0.f, 0.f, 0.f, 0.f};
  #pragma unroll
  for (int t = 0; t < T; ++t) {
    cm[t][0] = ub[t].x ? __expf(gsf[t] - mx[0]) : 0.f;
    cm[t][1] = ub[t].y ? __expf(gsf[t] - mx[1]) : 0.f;
    cm[t][2] = ub[t].z ? __expf(gsf[t] - mx[2]) : 0.f;
    cm[t][3] = ub[t].w ? __expf(gsf[t] - mx[3]) : 0.f;
    s += cm[t];
  }
  #pragma unroll
  for (int j = 0; j < 4; ++j) {
    s[j] += (s[j] < EPS) ? 1.f : 0.f;
    s[j] = 1.f / s[j];
  }
  f32x4 csum = {0.f, 0.f, 0.f, 0.f};
  #pragma unroll
  for (int t = 0; t < T; ++t) {
    cm[t] *= s;
    csum += cm[t];
  }

  if (cc == 0) {
    f32x4 cmask;
    #pragma unroll
    for (int j = 0; j < 4; ++j) cmask[j] = 1.f - csum[j];
    st4(out + ((size_t)b * 257 + 256) * HW + px, cmask);
    st4(out + (size_t)B * 257 * HW + (size_t)b * HW + px, cmask);
  }

  const float* vb = values + (size_t)(b * C + cc * 4) * Tt * HW;
  #pragma unroll
  for (int c = 0; c < 4; ++c) {
    int ch = cc * 4 + c;
    const float* vc = vb + (size_t)c * Tt * HW;
    f32x4 tf = ld4(vc + px);
    st4(out + ((size_t)b * 257 + ch) * HW + px, tf);   // exact t_feat copy
    f32x4 acc = {0.f, 0.f, 0.f, 0.f};
    #pragma unroll
    for (int t = 0; t < T; ++t) {
      f32x4 rf = ld4(vc + (t + 1) * HW + px);
      acc += rf * cm[t];
    }
    st4(out + ((size_t)b * 257 + 128 + ch) * HW + px, acc);
  }
}

extern "C" void kernel_launch(void* const* d_in, const int* in_sizes, int n_in,
                              void* d_out, int out_size, void* d_ws, size_t ws_size,
                              hipStream_t stream) {
  const float* values = (const float*)d_in[0];
  const float* tvmap  = (const float*)d_in[1];
  const float* rvmaps = (const float*)d_in[2];
  float* out = (float*)d_out;
  float* ws  = (float*)d_ws;

  hipLaunchKernelGGL(mask_kernel, dim3(512), dim3(256), 0, stream,
                     tvmap, rvmaps, ws);
  hipLaunchKernelGGL(gs_kernel, dim3(512), dim3(256), 0, stream,
                     values, ws);
  hipLaunchKernelGGL(out_kernel, dim3(1024), dim3(256), 0, stream,
                     values, ws, out);
}